// Round 2
// 230.994 us; speedup vs baseline: 1.1220x; 1.1220x over previous
//
#include <hip/hip_runtime.h>

// Problem constants (from reference setup_inputs):
//   spike_seq: (T=1024, B=16384, 2) fp32; w_exc: (1,2); w_inh: scalar.
// Outputs concatenated flat: spk_rec (T*B) then mem_rec (T*B), fp32.
#define T_LEN 1024
#define B_N   16384
#define UNROLL 32   // 32 outstanding 8B loads/lane = 16 KiB/wave in flight per phase

// One thread per neuron; sequential over T (reset nonlinearity forbids
// parallel scan). 256 blocks x 64 threads = 1 wave/CU. Latency hidden by
// ping-pong register prefetch whose issue order is PINNED with
// sched_barrier(0): [load B][compute+store A][load A][compute+store B].
// Rationale: vmcnt retires in-order, so a load issued after stores can't be
// waited on until the stores ack — the previous version let the compiler
// sink the prefetch into the store-bearing consume loop (VGPR_Count=44
// proved the buffers were collapsed), chaining every load-wait behind the
// prior batch's store drain.
__global__ __launch_bounds__(64, 1) void FMFMNeuronInhib_34033320854098_kernel(
    const float* __restrict__ x,      // (T, B, 2)
    const float* __restrict__ w_exc,  // 2 elements: {0.7, 1.0}
    const float* __restrict__ w_inh,  // 1 element: -1.0
    float* __restrict__ out) {
  // No FMA contraction: must round mul/add separately to bit-match the
  // numpy reference — a 1-ulp mem difference at the threshold flips a spike.
#pragma clang fp contract(off)
  const int b = blockIdx.x * 64 + threadIdx.x;
  const float w0 = w_exc[0];
  const float w1 = w_exc[1];
  const float wi = w_inh[0];

  float* __restrict__ spk_out = out;                          // [T*B]
  float* __restrict__ mem_out = out + (size_t)T_LEN * B_N;    // [T*B]
  const float2* __restrict__ xp = (const float2*)x + b;       // stride B_N float2 per t

  float mem = 0.0f;
  float inh = 0.0f;

  // Nontemporal stores: the 134 MB output stream must not evict the 134 MB
  // input from the 256 MB Infinity Cache (FETCH_SIZE showed the input was
  // only half-resident). Output is never re-read inside the timed region.
  auto step = [&](int t, float2 xv) {
#pragma clang fp contract(off)
    const float x0 = xv.x;
    const float x1 = xv.y;
    // cur_exc = x @ w_exc^T  (w1 = 1.0 -> exact)
    const float cur_exc = x0 * w0 + x1 * w1;
    // inh = 0.6*inh + x0
    inh = 0.6f * inh + x0;
    // cur = cur_exc + w_inh*inh  (wi = -1.0 -> exact negation)
    const float cur = cur_exc + wi * inh;
    // reset from PREVIOUS mem
    const float reset = (mem - 1.0f > 0.0f) ? 1.0f : 0.0f;
    // mem = 0.9*mem + cur - reset*1.0
    mem = 0.9f * mem + cur - reset * 1.0f;
    const float spk = (mem - 1.0f > 0.0f) ? 1.0f : 0.0f;
    __builtin_nontemporal_store(spk, &spk_out[(size_t)t * B_N + b]);
    __builtin_nontemporal_store(mem, &mem_out[(size_t)t * B_N + b]);
  };

  float2 bufA[UNROLL];
  float2 bufB[UNROLL];

  // Prologue: A <- t = 0..UNROLL-1.
#pragma unroll
  for (int u = 0; u < UNROLL; ++u) bufA[u] = xp[(size_t)u * B_N];
  __builtin_amdgcn_sched_barrier(0);

  for (int t0 = 0; t0 < T_LEN; t0 += 2 * UNROLL) {
    // Phase 1: issue B's loads (t0+UNROLL .. t0+2*UNROLL-1). Always in
    // range: t0 <= T_LEN - 2*UNROLL.
#pragma unroll
    for (int u = 0; u < UNROLL; ++u)
      bufB[u] = xp[(size_t)(t0 + UNROLL + u) * B_N];
    __builtin_amdgcn_sched_barrier(0);

    // Phase 2: consume A (its loads are older than every outstanding store).
#pragma unroll
    for (int u = 0; u < UNROLL; ++u) step(t0 + u, bufA[u]);
    __builtin_amdgcn_sched_barrier(0);

    // Phase 3: issue A's loads for the next iteration.
    if (t0 + 2 * UNROLL < T_LEN) {
#pragma unroll
      for (int u = 0; u < UNROLL; ++u)
        bufA[u] = xp[(size_t)(t0 + 2 * UNROLL + u) * B_N];
    }
    __builtin_amdgcn_sched_barrier(0);

    // Phase 4: consume B.
#pragma unroll
    for (int u = 0; u < UNROLL; ++u) step(t0 + UNROLL + u, bufB[u]);
    __builtin_amdgcn_sched_barrier(0);
  }
}

extern "C" void kernel_launch(void* const* d_in, const int* in_sizes, int n_in,
                              void* d_out, int out_size, void* d_ws, size_t ws_size,
                              hipStream_t stream) {
  const float* x     = (const float*)d_in[0];  // spike_seq, T*B*2 floats
  const float* w_exc = (const float*)d_in[1];  // 2 floats
  const float* w_inh = (const float*)d_in[2];  // 1 float
  float* out = (float*)d_out;                  // spk_rec ++ mem_rec

  dim3 grid(B_N / 64);  // 256 blocks -> 1 block (1 wave) per CU
  dim3 block(64);
  hipLaunchKernelGGL(FMFMNeuronInhib_34033320854098_kernel, grid, block, 0, stream,
                     x, w_exc, w_inh, out);
}